// Round 9
// baseline (121.193 us; speedup 1.0000x reference)
//
#include <hip/hip_runtime.h>
#include <math.h>

#define CAMS 6
#define CCH 256
#define HH 46
#define WW 80
#define NPIX (HH * WW)
#define HEADS 8
#define PIP 4
#define PP 4
#define KK 16
#define RADIUS_F 0.12f
#define NC 384        // combined qgemm output width: 256 offsets + 128 logits
#define FEATB (58 * 4 * CAMS)   // feat-transpose blocks in prep_k

__device__ __forceinline__ unsigned short f2bf(float f) {
    unsigned int x = __float_as_uint(f);
    unsigned int r = (x + 0x7FFFu + ((x >> 16) & 1u)) >> 16;  // RNE
    return (unsigned short)r;
}
__device__ __forceinline__ float bf2f(unsigned short u) {
    return __uint_as_float(((unsigned int)u) << 16);
}

// prep_k: blocks [0,FEATB) = LDS-tiled feat transpose+bf16 convert
//         blocks [FEATB, FEATB+40) = weight transposes into 4-row-interleaved
//         layout Wi[j/4][col][j%3..0]  (float4 per (j-group, col))
__global__ void __launch_bounds__(256) prep_k(const float* __restrict__ imfeat,
                                              unsigned short* __restrict__ feat_t,
                                              const float* __restrict__ offw,
                                              const float* __restrict__ ww,
                                              const float* __restrict__ outw,
                                              float* __restrict__ WCi,
                                              float* __restrict__ outTi) {
    __shared__ float tile[64][65];
    int b = blockIdx.x;
    int tj = threadIdx.x & 63;
    int ti = threadIdx.x >> 6;
    if (b < FEATB) {
        int px = b % 58, rest = b / 58;
        int r0 = (rest % 4) * 64;
        int cam = rest / 4;
        int p0 = px * 64;
        const float* src = imfeat + ((long)cam * CCH + r0) * NPIX + p0;
#pragma unroll
        for (int k = 0; k < 64; k += 4) {
            if (p0 + tj < NPIX) tile[ti + k][tj] = src[(long)(ti + k) * NPIX + tj];
        }
        __syncthreads();
        unsigned short* dst = feat_t + ((long)cam * NPIX + p0) * CCH + r0;
#pragma unroll
        for (int k = 0; k < 64; k += 4) {
            if (p0 + ti + k < NPIX) dst[(long)(ti + k) * CCH + tj] = f2bf(tile[tj][ti + k]);
        }
    } else {
        int c = b - FEATB;
        const float* src;
        float* dst;
        int tr, tc, dcols, dcol0;
        if (c < 16)      { src = offw; dst = WCi;   tr = c >> 2;        tc = c & 3;         dcols = NC;  dcol0 = 0; }
        else if (c < 24) { src = ww;   dst = WCi;   tr = (c - 16) & 1;  tc = (c - 16) >> 1; dcols = NC;  dcol0 = 256; }
        else             { src = outw; dst = outTi; tr = (c - 24) >> 2; tc = (c - 24) & 3;  dcols = 256; dcol0 = 0; }
#pragma unroll
        for (int k = 0; k < 64; k += 4)
            tile[ti + k][tj] = src[(long)(tr * 64 + ti + k) * CCH + tc * 64 + tj];
        __syncthreads();
        int col = dcol0 + tr * 64 + tj;
#pragma unroll
        for (int q = ti; q < 16; q += 4) {
            float4 v = make_float4(tile[tj][4 * q + 0], tile[tj][4 * q + 1],
                                   tile[tj][4 * q + 2], tile[tj][4 * q + 3]);
            ((float4*)dst)[(long)(tc * 16 + q) * dcols + col] = v;
        }
    }
}

// Dense layer 1: scalar-pipe activations + interleaved weights, no LDS.
// Block = 4 waves x (8 rows, 64 cols). Lane l owns col blockIdx.y*64+l.
// Per j-group: 1 coalesced float4 weight load + 8 s_load_dwordx4 (q rows,
// forced uniform via readfirstlane) + 32 FMA.
__global__ void __launch_bounds__(256) qgemm4_k(const float* __restrict__ query,
                                                const float* __restrict__ WCi,  // f4[64][NC]
                                                const float* __restrict__ offB,
                                                const float* __restrict__ wB,
                                                float* __restrict__ offsets,    // [N][256]
                                                float* __restrict__ wl,         // [N][128]
                                                int N) {
    int w = threadIdx.x >> 6, l = threadIdx.x & 63;
    int row0 = __builtin_amdgcn_readfirstlane(blockIdx.x * 32 + w * 8);
    int col = blockIdx.y * 64 + l;

    const float* qr[8];
#pragma unroll
    for (int r = 0; r < 8; r++) qr[r] = query + (long)min(row0 + r, N - 1) * CCH;

    const float4* wp = (const float4*)WCi + col;
    float acc[8] = {0.f, 0.f, 0.f, 0.f, 0.f, 0.f, 0.f, 0.f};
#pragma unroll 2
    for (int jg = 0; jg < 64; jg++) {
        float4 wv = wp[(long)jg * NC];
#pragma unroll
        for (int r = 0; r < 8; r++) {
            float4 qv = *(const float4*)(qr[r] + jg * 4);
            acc[r] = fmaf(qv.w, wv.w, fmaf(qv.z, wv.z, fmaf(qv.y, wv.y, fmaf(qv.x, wv.x, acc[r]))));
        }
    }

    if (col < 256) {
        float b = offB[col];
#pragma unroll
        for (int r = 0; r < 8; r++) {
            int gm = row0 + r;
            if (gm < N) offsets[(long)gm * CCH + col] = tanhf(acc[r] + b) * RADIUS_F;
        }
    } else {
        int c2 = col - 256;
        float b = wB[c2];
#pragma unroll
        for (int r = 0; r < 8; r++) {
            int gm = row0 + r;
            if (gm < N) wl[(long)gm * 128 + c2] = acc[r] + b;
        }
    }
}

// Per-(cam,query) sampling. One wave per task; tasks cam-major, partitioned
// into 8 contiguous ranges pinned to XCDs via blockIdx%8 (round-robin
// dispatch). Each XCD touches <=2 cams (<=3.7 MB bf16) -> L2-resident.
__global__ void __launch_bounds__(256, 4) sample_cam_k(
        const unsigned short* __restrict__ feat_t,  // [CAMS][NPIX][CCH] bf16
        const float* __restrict__ refp,             // [CAMS][N][PIP][2]
        const int* __restrict__ bev,                // [CAMS][N][PIP]
        const float* __restrict__ offsets,          // [N][256]
        const float* __restrict__ wl,               // [N][128]
        float* __restrict__ cam_out,                // [CAMS][N][256]
        int N, int per_xcd) {
    int xcd = blockIdx.x & 7;
    int local = (blockIdx.x >> 3) * 4 + (threadIdx.x >> 6);
    if (local >= per_xcd) return;
    long task = (long)xcd * per_xcd + local;
    if (task >= (long)CAMS * N) return;
    int cam = (int)(task / N);
    int n = (int)(task - (long)cam * N);

    int l = threadIdx.x & 63;
    int h = l >> 3;

    const int* bv = bev + ((long)cam * N + n) * 4;
    int m0 = bv[0], m1 = bv[1], m2 = bv[2], m3 = bv[3];
    float* outp = cam_out + ((long)cam * N + n) * CCH + (l << 2);
    if (!(m0 | m1 | m2 | m3)) {
        *(float4*)outp = make_float4(0.f, 0.f, 0.f, 0.f);
        return;
    }

    const float* rp = refp + ((long)cam * N + n) * 8;
    const float4* offn = (const float4*)(offsets + (long)n * CCH + (h << 5));
    const float4* wln = (const float4*)(wl + (long)n * 128 + (h << 4));

    float4 wl0, wl1, wl2, wl3;
    float mmax = -1e30f;
    if (m0) { wl0 = wln[0]; mmax = fmaxf(mmax, fmaxf(fmaxf(wl0.x, wl0.y), fmaxf(wl0.z, wl0.w))); }
    if (m1) { wl1 = wln[1]; mmax = fmaxf(mmax, fmaxf(fmaxf(wl1.x, wl1.y), fmaxf(wl1.z, wl1.w))); }
    if (m2) { wl2 = wln[2]; mmax = fmaxf(mmax, fmaxf(fmaxf(wl2.x, wl2.y), fmaxf(wl2.z, wl2.w))); }
    if (m3) { wl3 = wln[3]; mmax = fmaxf(mmax, fmaxf(fmaxf(wl3.x, wl3.y), fmaxf(wl3.z, wl3.w))); }

    float w_[KK];
#pragma unroll
    for (int k = 0; k < KK; k++) w_[k] = 0.f;
    float ssum = 0.f;
    if (m0) {
        w_[0] = __expf(wl0.x - mmax); w_[1] = __expf(wl0.y - mmax);
        w_[2] = __expf(wl0.z - mmax); w_[3] = __expf(wl0.w - mmax);
        ssum += w_[0] + w_[1] + w_[2] + w_[3];
    }
    if (m1) {
        w_[4] = __expf(wl1.x - mmax); w_[5] = __expf(wl1.y - mmax);
        w_[6] = __expf(wl1.z - mmax); w_[7] = __expf(wl1.w - mmax);
        ssum += w_[4] + w_[5] + w_[6] + w_[7];
    }
    if (m2) {
        w_[8] = __expf(wl2.x - mmax); w_[9] = __expf(wl2.y - mmax);
        w_[10] = __expf(wl2.z - mmax); w_[11] = __expf(wl2.w - mmax);
        ssum += w_[8] + w_[9] + w_[10] + w_[11];
    }
    if (m3) {
        w_[12] = __expf(wl3.x - mmax); w_[13] = __expf(wl3.y - mmax);
        w_[14] = __expf(wl3.z - mmax); w_[15] = __expf(wl3.w - mmax);
        ssum += w_[12] + w_[13] + w_[14] + w_[15];
    }
    float inv = 1.f / ssum;

    const ushort4* fcam = (const ushort4*)(feat_t + (long)cam * NPIX * CCH) + l;
    float ax = 0.f, ay = 0.f, az = 0.f, aw = 0.f;

#pragma unroll
    for (int pip = 0; pip < PIP; pip++) {
        int vis = (pip == 0) ? m0 : (pip == 1) ? m1 : (pip == 2) ? m2 : m3;
        if (!vis) continue;
        float rx = rp[pip * 2 + 0];
        float ry = rp[pip * 2 + 1];
        float4 oa = offn[pip * 2];
        float4 ob = offn[pip * 2 + 1];
        float px[PP] = {oa.x, oa.z, ob.x, ob.z};
        float py[PP] = {oa.y, oa.w, ob.y, ob.w};
#pragma unroll
        for (int p = 0; p < PP; p++) {
            float wgt = w_[pip * PP + p];
            float x = fmaf(rx + px[p], (float)WW, -0.5f);
            float y = fmaf(ry + py[p], (float)HH, -0.5f);
            float x0f = floorf(x), y0f = floorf(y);
            float fx = x - x0f, fy = y - y0f;
            int ix = (int)x0f, iy = (int)y0f;
            int ix0 = min(max(ix, 0), WW - 1);
            int ix1 = min(max(ix + 1, 0), WW - 1);
            int iy0 = min(max(iy, 0), HH - 1);
            int iy1 = min(max(iy + 1, 0), HH - 1);
            float wx0 = (1.f - fx) * (((ix >= 0) & (ix < WW)) ? 1.f : 0.f);
            float wx1 = fx * (((ix + 1 >= 0) & (ix + 1 < WW)) ? 1.f : 0.f);
            float wy0 = (1.f - fy) * (((iy >= 0) & (iy < HH)) ? 1.f : 0.f);
            float wy1 = fy * (((iy + 1 >= 0) & (iy + 1 < HH)) ? 1.f : 0.f);
            const ushort4 u00 = fcam[(iy0 * WW + ix0) * (CCH / 4)];
            const ushort4 u01 = fcam[(iy0 * WW + ix1) * (CCH / 4)];
            const ushort4 u10 = fcam[(iy1 * WW + ix0) * (CCH / 4)];
            const ushort4 u11 = fcam[(iy1 * WW + ix1) * (CCH / 4)];
            float a00 = wgt * wy0 * wx0;
            float a01 = wgt * wy0 * wx1;
            float a10 = wgt * wy1 * wx0;
            float a11 = wgt * wy1 * wx1;
            ax = fmaf(a00, bf2f(u00.x), ax); ay = fmaf(a00, bf2f(u00.y), ay);
            az = fmaf(a00, bf2f(u00.z), az); aw = fmaf(a00, bf2f(u00.w), aw);
            ax = fmaf(a01, bf2f(u01.x), ax); ay = fmaf(a01, bf2f(u01.y), ay);
            az = fmaf(a01, bf2f(u01.z), az); aw = fmaf(a01, bf2f(u01.w), aw);
            ax = fmaf(a10, bf2f(u10.x), ax); ay = fmaf(a10, bf2f(u10.y), ay);
            az = fmaf(a10, bf2f(u10.z), az); aw = fmaf(a10, bf2f(u10.w), aw);
            ax = fmaf(a11, bf2f(u11.x), ax); ay = fmaf(a11, bf2f(u11.y), ay);
            az = fmaf(a11, bf2f(u11.z), az); aw = fmaf(a11, bf2f(u11.w), aw);
        }
    }
    *(float4*)outp = make_float4(ax * inv, ay * inv, az * inv, aw * inv);
}

// fsum[n][c] = sum_cam cam_out[cam][n][c]  (f32, float4 grid-stride-free)
__global__ void __launch_bounds__(256) camsum_k(const float* __restrict__ cam_out,
                                                float* __restrict__ fsum, int N) {
    int idx = blockIdx.x * 256 + threadIdx.x;
    int total = N * (CCH / 4);
    if (idx >= total) return;
    const float4* src = (const float4*)cam_out;
    float4 s = make_float4(0.f, 0.f, 0.f, 0.f);
#pragma unroll
    for (int cam = 0; cam < CAMS; cam++) {
        float4 v = src[(long)cam * total + idx];
        s.x += v.x; s.y += v.y; s.z += v.z; s.w += v.w;
    }
    ((float4*)fsum)[idx] = s;
}

// Dense layer 2: same scalar-pipe GEMM over fsum; 1/count via scalar bev
// loads + SALU in the prologue, folded into the epilogue.
__global__ void __launch_bounds__(256) outproj4_k(const float* __restrict__ fsum,
                                                  const int* __restrict__ bev,
                                                  const float* __restrict__ outTi, // f4[64][256]
                                                  const float* __restrict__ outB,
                                                  float* __restrict__ out, int N) {
    int w = threadIdx.x >> 6, l = threadIdx.x & 63;
    int row0 = __builtin_amdgcn_readfirstlane(blockIdx.x * 32 + w * 8);
    int col = blockIdx.y * 64 + l;

    const float* fr[8];
    float invc[8];
#pragma unroll
    for (int r = 0; r < 8; r++) {
        int rr = min(row0 + r, N - 1);
        fr[r] = fsum + (long)rr * CCH;
        int cnt = 0;
#pragma unroll
        for (int cam = 0; cam < CAMS; cam++) {
            const int* bv = bev + ((long)cam * N + rr) * 4;
            cnt += (bv[0] | bv[1] | bv[2] | bv[3]) ? 1 : 0;
        }
        invc[r] = 1.f / (float)max(cnt, 1);
    }

    const float4* wp = (const float4*)outTi + col;
    float acc[8] = {0.f, 0.f, 0.f, 0.f, 0.f, 0.f, 0.f, 0.f};
#pragma unroll 2
    for (int jg = 0; jg < 64; jg++) {
        float4 wv = wp[(long)jg * CCH];
#pragma unroll
        for (int r = 0; r < 8; r++) {
            float4 qv = *(const float4*)(fr[r] + jg * 4);
            acc[r] = fmaf(qv.w, wv.w, fmaf(qv.z, wv.z, fmaf(qv.y, wv.y, fmaf(qv.x, wv.x, acc[r]))));
        }
    }

    float b = outB[col];
#pragma unroll
    for (int r = 0; r < 8; r++) {
        int gm = row0 + r;
        if (gm < N) out[(long)gm * CCH + col] = fmaf(acc[r], invc[r], b);
    }
}

extern "C" void kernel_launch(void* const* d_in, const int* in_sizes, int n_in,
                              void* d_out, int out_size, void* d_ws, size_t ws_size,
                              hipStream_t stream) {
    const float* query    = (const float*)d_in[0];
    const float* imfeat   = (const float*)d_in[1];
    const float* refp     = (const float*)d_in[2];
    const int*   bev      = (const int*)d_in[3];
    const float* offset_w = (const float*)d_in[4];
    const float* offset_b = (const float*)d_in[5];
    const float* weight_w = (const float*)d_in[6];
    const float* weight_b = (const float*)d_in[7];
    const float* out_w    = (const float*)d_in[8];
    const float* out_b    = (const float*)d_in[9];
    float* out = (float*)d_out;

    int N = in_sizes[0] / CCH;  // 2500

    float* ws = (float*)d_ws;
    unsigned short* feat_t = (unsigned short*)ws;              // 6*3680*256 bf16
    float* WCi    = ws + (size_t)CAMS * NPIX * CCH / 2;        // 256*384 (interleaved)
    float* outTi  = WCi + (size_t)CCH * NC;                    // 256*256 (interleaved)
    float* offs   = outTi + (size_t)CCH * CCH;                 // N*256
    float* wl     = offs + (size_t)N * CCH;                    // N*128
    float* camob  = wl + (size_t)N * 128;                      // CAMS*N*256
    float* fsum   = camob + (size_t)CAMS * N * CCH;            // N*256

    prep_k<<<FEATB + 40, 256, 0, stream>>>(imfeat, feat_t, offset_w, weight_w, out_w,
                                           WCi, outTi);

    int mblocks = (N + 31) / 32;   // 79
    qgemm4_k<<<dim3(mblocks, 6), 256, 0, stream>>>(query, WCi, offset_b, weight_b,
                                                   offs, wl, N);

    int T = CAMS * N;
    int per_xcd = (T + 7) / 8;
    int blocks = 8 * ((per_xcd + 3) / 4);
    sample_cam_k<<<blocks, 256, 0, stream>>>(feat_t, refp, bev, offs, wl, camob,
                                             N, per_xcd);

    camsum_k<<<(N * (CCH / 4) + 255) / 256, 256, 0, stream>>>(camob, fsum, N);

    outproj4_k<<<dim3(mblocks, 4), 256, 0, stream>>>(fsum, bev, outTi, out_b, out, N);
}

// Round 10
// 92.302 us; speedup vs baseline: 1.3130x; 1.3130x over previous
//
#include <hip/hip_runtime.h>
#include <math.h>

#define CAMS 6
#define CCH 256
#define HH 46
#define WW 80
#define NPIX (HH * WW)
#define HEADS 8
#define PIP 4
#define PP 4
#define KK 16
#define RADIUS_F 0.12f
#define NC 384        // combined qgemm output width: 256 offsets + 128 logits
#define FEATB (58 * 4 * CAMS)   // feat-transpose blocks in prep_k

__device__ __forceinline__ unsigned short f2bf(float f) {
    unsigned int x = __float_as_uint(f);
    unsigned int r = (x + 0x7FFFu + ((x >> 16) & 1u)) >> 16;  // RNE
    return (unsigned short)r;
}
__device__ __forceinline__ float bf2f(unsigned short u) {
    return __uint_as_float(((unsigned int)u) << 16);
}

// prep_k: blocks [0,FEATB) = LDS-tiled feat transpose+bf16 convert
//         blocks [FEATB, FEATB+40) = weight transposes into 4-row-interleaved
//         float4 layout Wi[jg][col] = W[col][4jg..4jg+3]
__global__ void __launch_bounds__(256) prep_k(const float* __restrict__ imfeat,
                                              unsigned short* __restrict__ feat_t,
                                              const float* __restrict__ offw,
                                              const float* __restrict__ ww,
                                              const float* __restrict__ outw,
                                              float* __restrict__ WCi,
                                              float* __restrict__ outTi) {
    __shared__ float tile[64][65];
    int b = blockIdx.x;
    int tj = threadIdx.x & 63;
    int ti = threadIdx.x >> 6;
    if (b < FEATB) {
        int px = b % 58, rest = b / 58;
        int r0 = (rest % 4) * 64;
        int cam = rest / 4;
        int p0 = px * 64;
        const float* src = imfeat + ((long)cam * CCH + r0) * NPIX + p0;
#pragma unroll
        for (int k = 0; k < 64; k += 4) {
            if (p0 + tj < NPIX) tile[ti + k][tj] = src[(long)(ti + k) * NPIX + tj];
        }
        __syncthreads();
        unsigned short* dst = feat_t + ((long)cam * NPIX + p0) * CCH + r0;
#pragma unroll
        for (int k = 0; k < 64; k += 4) {
            if (p0 + ti + k < NPIX) dst[(long)(ti + k) * CCH + tj] = f2bf(tile[tj][ti + k]);
        }
    } else {
        int c = b - FEATB;
        const float* src;
        float* dst;
        int tr, tc, dcols, dcol0;
        if (c < 16)      { src = offw; dst = WCi;   tr = c >> 2;        tc = c & 3;         dcols = NC;  dcol0 = 0; }
        else if (c < 24) { src = ww;   dst = WCi;   tr = (c - 16) & 1;  tc = (c - 16) >> 1; dcols = NC;  dcol0 = 256; }
        else             { src = outw; dst = outTi; tr = (c - 24) >> 2; tc = (c - 24) & 3;  dcols = 256; dcol0 = 0; }
#pragma unroll
        for (int k = 0; k < 64; k += 4)
            tile[ti + k][tj] = src[(long)(tr * 64 + ti + k) * CCH + tc * 64 + tj];
        __syncthreads();
        int col = dcol0 + tr * 64 + tj;
#pragma unroll
        for (int q = ti; q < 16; q += 4) {
            float4 v = make_float4(tile[tj][4 * q + 0], tile[tj][4 * q + 1],
                                   tile[tj][4 * q + 2], tile[tj][4 * q + 3]);
            ((float4*)dst)[(long)(tc * 16 + q) * dcols + col] = v;
        }
    }
}

// Dense layer 1, hand-pipelined: 32 rows x 64 cols per block. A-tile staged
// in LDS once ([Kgrp][row], pad 33 -> conflict-free writes, uniform-address
// broadcast reads). Weights via interleaved float4 (1 load = 4 K-values),
// explicitly double-buffered in named registers (wreg/wnext) so 4 loads stay
// in flight across each 128-FMA compute group.
__global__ void __launch_bounds__(256) qgemm5_k(const float* __restrict__ query,
                                                const float* __restrict__ WCi,  // f4[64][NC]
                                                const float* __restrict__ offB,
                                                const float* __restrict__ wB,
                                                float* __restrict__ offsets,    // [N][256]
                                                float* __restrict__ wl,         // [N][128]
                                                int N) {
    __shared__ float4 qt[64][33];   // [Kgrp][row]
    int w = threadIdx.x >> 6, l = threadIdx.x & 63;
    int m0 = blockIdx.x * 32;
    int col = blockIdx.y * 64 + l;    // 0..383

#pragma unroll
    for (int i = 0; i < 8; i++) {
        int mm = i * 4 + w;           // wave-uniform
        int gm = m0 + mm;
        float4 v = make_float4(0.f, 0.f, 0.f, 0.f);
        if (gm < N) v = *(const float4*)(query + (long)gm * CCH + (l << 2));
        qt[l][mm] = v;
    }
    __syncthreads();

    int mb = w * 8;
    const float4* wp = (const float4*)WCi + col;
    float4 wreg0 = wp[0];
    float4 wreg1 = wp[(long)1 * NC];
    float4 wreg2 = wp[(long)2 * NC];
    float4 wreg3 = wp[(long)3 * NC];
    float acc[8] = {0.f, 0.f, 0.f, 0.f, 0.f, 0.f, 0.f, 0.f};
    for (int jg0 = 0; jg0 < 64; jg0 += 4) {
        int pre = (jg0 + 4) & 63;     // wrap on last iter (harmless re-read)
        float4 wn0 = wp[(long)(pre + 0) * NC];
        float4 wn1 = wp[(long)(pre + 1) * NC];
        float4 wn2 = wp[(long)(pre + 2) * NC];
        float4 wn3 = wp[(long)(pre + 3) * NC];
#pragma unroll
        for (int r = 0; r < 8; r++) {
            float4 qv = qt[jg0 + 0][mb + r];
            acc[r] = fmaf(qv.w, wreg0.w, fmaf(qv.z, wreg0.z, fmaf(qv.y, wreg0.y, fmaf(qv.x, wreg0.x, acc[r]))));
        }
#pragma unroll
        for (int r = 0; r < 8; r++) {
            float4 qv = qt[jg0 + 1][mb + r];
            acc[r] = fmaf(qv.w, wreg1.w, fmaf(qv.z, wreg1.z, fmaf(qv.y, wreg1.y, fmaf(qv.x, wreg1.x, acc[r]))));
        }
#pragma unroll
        for (int r = 0; r < 8; r++) {
            float4 qv = qt[jg0 + 2][mb + r];
            acc[r] = fmaf(qv.w, wreg2.w, fmaf(qv.z, wreg2.z, fmaf(qv.y, wreg2.y, fmaf(qv.x, wreg2.x, acc[r]))));
        }
#pragma unroll
        for (int r = 0; r < 8; r++) {
            float4 qv = qt[jg0 + 3][mb + r];
            acc[r] = fmaf(qv.w, wreg3.w, fmaf(qv.z, wreg3.z, fmaf(qv.y, wreg3.y, fmaf(qv.x, wreg3.x, acc[r]))));
        }
        wreg0 = wn0; wreg1 = wn1; wreg2 = wn2; wreg3 = wn3;
    }

    if (col < 256) {
        float b = offB[col];
#pragma unroll
        for (int r = 0; r < 8; r++) {
            int gm = m0 + mb + r;
            if (gm < N) offsets[(long)gm * CCH + col] = tanhf(acc[r] + b) * RADIUS_F;
        }
    } else {
        int c2 = col - 256;
        float b = wB[c2];
#pragma unroll
        for (int r = 0; r < 8; r++) {
            int gm = m0 + mb + r;
            if (gm < N) wl[(long)gm * 128 + c2] = acc[r] + b;
        }
    }
}

// Per-(cam,query) sampling. One wave per task; tasks cam-major, partitioned
// into 8 contiguous ranges pinned to XCDs via blockIdx%8 (round-robin
// dispatch). Each XCD touches <=2 cams (<=3.7 MB bf16) -> L2-resident.
__global__ void __launch_bounds__(256, 4) sample_cam_k(
        const unsigned short* __restrict__ feat_t,  // [CAMS][NPIX][CCH] bf16
        const float* __restrict__ refp,             // [CAMS][N][PIP][2]
        const int* __restrict__ bev,                // [CAMS][N][PIP]
        const float* __restrict__ offsets,          // [N][256]
        const float* __restrict__ wl,               // [N][128]
        float* __restrict__ cam_out,                // [CAMS][N][256]
        int N, int per_xcd) {
    int xcd = blockIdx.x & 7;
    int local = (blockIdx.x >> 3) * 4 + (threadIdx.x >> 6);
    if (local >= per_xcd) return;
    long task = (long)xcd * per_xcd + local;
    if (task >= (long)CAMS * N) return;
    int cam = (int)(task / N);
    int n = (int)(task - (long)cam * N);

    int l = threadIdx.x & 63;
    int h = l >> 3;

    const int* bv = bev + ((long)cam * N + n) * 4;
    int m0 = bv[0], m1 = bv[1], m2 = bv[2], m3 = bv[3];
    float* outp = cam_out + ((long)cam * N + n) * CCH + (l << 2);
    if (!(m0 | m1 | m2 | m3)) {
        *(float4*)outp = make_float4(0.f, 0.f, 0.f, 0.f);
        return;
    }

    const float* rp = refp + ((long)cam * N + n) * 8;
    const float4* offn = (const float4*)(offsets + (long)n * CCH + (h << 5));
    const float4* wln = (const float4*)(wl + (long)n * 128 + (h << 4));

    float4 wl0, wl1, wl2, wl3;
    float mmax = -1e30f;
    if (m0) { wl0 = wln[0]; mmax = fmaxf(mmax, fmaxf(fmaxf(wl0.x, wl0.y), fmaxf(wl0.z, wl0.w))); }
    if (m1) { wl1 = wln[1]; mmax = fmaxf(mmax, fmaxf(fmaxf(wl1.x, wl1.y), fmaxf(wl1.z, wl1.w))); }
    if (m2) { wl2 = wln[2]; mmax = fmaxf(mmax, fmaxf(fmaxf(wl2.x, wl2.y), fmaxf(wl2.z, wl2.w))); }
    if (m3) { wl3 = wln[3]; mmax = fmaxf(mmax, fmaxf(fmaxf(wl3.x, wl3.y), fmaxf(wl3.z, wl3.w))); }

    float w_[KK];
#pragma unroll
    for (int k = 0; k < KK; k++) w_[k] = 0.f;
    float ssum = 0.f;
    if (m0) {
        w_[0] = __expf(wl0.x - mmax); w_[1] = __expf(wl0.y - mmax);
        w_[2] = __expf(wl0.z - mmax); w_[3] = __expf(wl0.w - mmax);
        ssum += w_[0] + w_[1] + w_[2] + w_[3];
    }
    if (m1) {
        w_[4] = __expf(wl1.x - mmax); w_[5] = __expf(wl1.y - mmax);
        w_[6] = __expf(wl1.z - mmax); w_[7] = __expf(wl1.w - mmax);
        ssum += w_[4] + w_[5] + w_[6] + w_[7];
    }
    if (m2) {
        w_[8] = __expf(wl2.x - mmax); w_[9] = __expf(wl2.y - mmax);
        w_[10] = __expf(wl2.z - mmax); w_[11] = __expf(wl2.w - mmax);
        ssum += w_[8] + w_[9] + w_[10] + w_[11];
    }
    if (m3) {
        w_[12] = __expf(wl3.x - mmax); w_[13] = __expf(wl3.y - mmax);
        w_[14] = __expf(wl3.z - mmax); w_[15] = __expf(wl3.w - mmax);
        ssum += w_[12] + w_[13] + w_[14] + w_[15];
    }
    float inv = 1.f / ssum;

    const ushort4* fcam = (const ushort4*)(feat_t + (long)cam * NPIX * CCH) + l;
    float ax = 0.f, ay = 0.f, az = 0.f, aw = 0.f;

#pragma unroll
    for (int pip = 0; pip < PIP; pip++) {
        int vis = (pip == 0) ? m0 : (pip == 1) ? m1 : (pip == 2) ? m2 : m3;
        if (!vis) continue;
        float rx = rp[pip * 2 + 0];
        float ry = rp[pip * 2 + 1];
        float4 oa = offn[pip * 2];
        float4 ob = offn[pip * 2 + 1];
        float px[PP] = {oa.x, oa.z, ob.x, ob.z};
        float py[PP] = {oa.y, oa.w, ob.y, ob.w};
#pragma unroll
        for (int p = 0; p < PP; p++) {
            float wgt = w_[pip * PP + p];
            float x = fmaf(rx + px[p], (float)WW, -0.5f);
            float y = fmaf(ry + py[p], (float)HH, -0.5f);
            float x0f = floorf(x), y0f = floorf(y);
            float fx = x - x0f, fy = y - y0f;
            int ix = (int)x0f, iy = (int)y0f;
            int ix0 = min(max(ix, 0), WW - 1);
            int ix1 = min(max(ix + 1, 0), WW - 1);
            int iy0 = min(max(iy, 0), HH - 1);
            int iy1 = min(max(iy + 1, 0), HH - 1);
            float wx0 = (1.f - fx) * (((ix >= 0) & (ix < WW)) ? 1.f : 0.f);
            float wx1 = fx * (((ix + 1 >= 0) & (ix + 1 < WW)) ? 1.f : 0.f);
            float wy0 = (1.f - fy) * (((iy >= 0) & (iy < HH)) ? 1.f : 0.f);
            float wy1 = fy * (((iy + 1 >= 0) & (iy + 1 < HH)) ? 1.f : 0.f);
            const ushort4 u00 = fcam[(iy0 * WW + ix0) * (CCH / 4)];
            const ushort4 u01 = fcam[(iy0 * WW + ix1) * (CCH / 4)];
            const ushort4 u10 = fcam[(iy1 * WW + ix0) * (CCH / 4)];
            const ushort4 u11 = fcam[(iy1 * WW + ix1) * (CCH / 4)];
            float a00 = wgt * wy0 * wx0;
            float a01 = wgt * wy0 * wx1;
            float a10 = wgt * wy1 * wx0;
            float a11 = wgt * wy1 * wx1;
            ax = fmaf(a00, bf2f(u00.x), ax); ay = fmaf(a00, bf2f(u00.y), ay);
            az = fmaf(a00, bf2f(u00.z), az); aw = fmaf(a00, bf2f(u00.w), aw);
            ax = fmaf(a01, bf2f(u01.x), ax); ay = fmaf(a01, bf2f(u01.y), ay);
            az = fmaf(a01, bf2f(u01.z), az); aw = fmaf(a01, bf2f(u01.w), aw);
            ax = fmaf(a10, bf2f(u10.x), ax); ay = fmaf(a10, bf2f(u10.y), ay);
            az = fmaf(a10, bf2f(u10.z), az); aw = fmaf(a10, bf2f(u10.w), aw);
            ax = fmaf(a11, bf2f(u11.x), ax); ay = fmaf(a11, bf2f(u11.y), ay);
            az = fmaf(a11, bf2f(u11.z), az); aw = fmaf(a11, bf2f(u11.w), aw);
        }
    }
    *(float4*)outp = make_float4(ax * inv, ay * inv, az * inv, aw * inv);
}

// fsum[n][c] = sum_cam cam_out[cam][n][c]
__global__ void __launch_bounds__(256) camsum_k(const float* __restrict__ cam_out,
                                                float* __restrict__ fsum, int N) {
    int idx = blockIdx.x * 256 + threadIdx.x;
    int total = N * (CCH / 4);
    if (idx >= total) return;
    const float4* src = (const float4*)cam_out;
    float4 s = make_float4(0.f, 0.f, 0.f, 0.f);
#pragma unroll
    for (int cam = 0; cam < CAMS; cam++) {
        float4 v = src[(long)cam * total + idx];
        s.x += v.x; s.y += v.y; s.z += v.z; s.w += v.w;
    }
    ((float4*)fsum)[idx] = s;
}

// Dense layer 2, hand-pipelined (same structure as qgemm5); 1/count folded
// into the epilogue via LDS inv_s.
__global__ void __launch_bounds__(256) outproj5_k(const float* __restrict__ fsum,
                                                  const int* __restrict__ bev,
                                                  const float* __restrict__ outTi, // f4[64][256]
                                                  const float* __restrict__ outB,
                                                  float* __restrict__ out, int N) {
    __shared__ float4 ft[64][33];
    __shared__ float inv_s[32];
    int t = threadIdx.x;
    int w = t >> 6, l = t & 63;
    int m0 = blockIdx.x * 32;
    int col = blockIdx.y * 64 + l;    // 0..255

    if (t < 32) {
        int gm = m0 + t;
        int cnt = 0;
        if (gm < N) {
#pragma unroll
            for (int cam = 0; cam < CAMS; cam++) {
                const int* bv = bev + ((long)cam * N + gm) * 4;
                cnt += (bv[0] | bv[1] | bv[2] | bv[3]) ? 1 : 0;
            }
        }
        inv_s[t] = 1.f / (float)max(cnt, 1);
    }
#pragma unroll
    for (int i = 0; i < 8; i++) {
        int mm = i * 4 + w;           // wave-uniform
        int gm = m0 + mm;
        float4 v = make_float4(0.f, 0.f, 0.f, 0.f);
        if (gm < N) v = *(const float4*)(fsum + (long)gm * CCH + (l << 2));
        ft[l][mm] = v;
    }
    __syncthreads();

    int mb = w * 8;
    const float4* wp = (const float4*)outTi + col;
    float4 wreg0 = wp[0];
    float4 wreg1 = wp[(long)1 * CCH];
    float4 wreg2 = wp[(long)2 * CCH];
    float4 wreg3 = wp[(long)3 * CCH];
    float acc[8] = {0.f, 0.f, 0.f, 0.f, 0.f, 0.f, 0.f, 0.f};
    for (int jg0 = 0; jg0 < 64; jg0 += 4) {
        int pre = (jg0 + 4) & 63;
        float4 wn0 = wp[(long)(pre + 0) * CCH];
        float4 wn1 = wp[(long)(pre + 1) * CCH];
        float4 wn2 = wp[(long)(pre + 2) * CCH];
        float4 wn3 = wp[(long)(pre + 3) * CCH];
#pragma unroll
        for (int r = 0; r < 8; r++) {
            float4 qv = ft[jg0 + 0][mb + r];
            acc[r] = fmaf(qv.w, wreg0.w, fmaf(qv.z, wreg0.z, fmaf(qv.y, wreg0.y, fmaf(qv.x, wreg0.x, acc[r]))));
        }
#pragma unroll
        for (int r = 0; r < 8; r++) {
            float4 qv = ft[jg0 + 1][mb + r];
            acc[r] = fmaf(qv.w, wreg1.w, fmaf(qv.z, wreg1.z, fmaf(qv.y, wreg1.y, fmaf(qv.x, wreg1.x, acc[r]))));
        }
#pragma unroll
        for (int r = 0; r < 8; r++) {
            float4 qv = ft[jg0 + 2][mb + r];
            acc[r] = fmaf(qv.w, wreg2.w, fmaf(qv.z, wreg2.z, fmaf(qv.y, wreg2.y, fmaf(qv.x, wreg2.x, acc[r]))));
        }
#pragma unroll
        for (int r = 0; r < 8; r++) {
            float4 qv = ft[jg0 + 3][mb + r];
            acc[r] = fmaf(qv.w, wreg3.w, fmaf(qv.z, wreg3.z, fmaf(qv.y, wreg3.y, fmaf(qv.x, wreg3.x, acc[r]))));
        }
        wreg0 = wn0; wreg1 = wn1; wreg2 = wn2; wreg3 = wn3;
    }

    float b = outB[col];
#pragma unroll
    for (int r = 0; r < 8; r++) {
        int gm = m0 + mb + r;
        if (gm < N) out[(long)gm * CCH + col] = fmaf(acc[r], inv_s[mb + r], b);
    }
}

extern "C" void kernel_launch(void* const* d_in, const int* in_sizes, int n_in,
                              void* d_out, int out_size, void* d_ws, size_t ws_size,
                              hipStream_t stream) {
    const float* query    = (const float*)d_in[0];
    const float* imfeat   = (const float*)d_in[1];
    const float* refp     = (const float*)d_in[2];
    const int*   bev      = (const int*)d_in[3];
    const float* offset_w = (const float*)d_in[4];
    const float* offset_b = (const float*)d_in[5];
    const float* weight_w = (const float*)d_in[6];
    const float* weight_b = (const float*)d_in[7];
    const float* out_w    = (const float*)d_in[8];
    const float* out_b    = (const float*)d_in[9];
    float* out = (float*)d_out;

    int N = in_sizes[0] / CCH;  // 2500

    float* ws = (float*)d_ws;
    unsigned short* feat_t = (unsigned short*)ws;              // 6*3680*256 bf16
    float* WCi    = ws + (size_t)CAMS * NPIX * CCH / 2;        // 256*384 (interleaved f4)
    float* outTi  = WCi + (size_t)CCH * NC;                    // 256*256 (interleaved f4)
    float* offs   = outTi + (size_t)CCH * CCH;                 // N*256
    float* wl     = offs + (size_t)N * CCH;                    // N*128
    float* camob  = wl + (size_t)N * 128;                      // CAMS*N*256
    float* fsum   = camob + (size_t)CAMS * N * CCH;            // N*256

    prep_k<<<FEATB + 40, 256, 0, stream>>>(imfeat, feat_t, offset_w, weight_w, out_w,
                                           WCi, outTi);

    int mblocks = (N + 31) / 32;   // 79
    qgemm5_k<<<dim3(mblocks, 6), 256, 0, stream>>>(query, WCi, offset_b, weight_b,
                                                   offs, wl, N);

    int T = CAMS * N;
    int per_xcd = (T + 7) / 8;
    int blocks = 8 * ((per_xcd + 3) / 4);
    sample_cam_k<<<blocks, 256, 0, stream>>>(feat_t, refp, bev, offs, wl, camob,
                                             N, per_xcd);

    camsum_k<<<(N * (CCH / 4) + 255) / 256, 256, 0, stream>>>(camob, fsum, N);

    outproj5_k<<<dim3(mblocks, 4), 256, 0, stream>>>(fsum, bev, outTi, out_b, out, N);
}

// Round 11
// 90.656 us; speedup vs baseline: 1.3368x; 1.0182x over previous
//
#include <hip/hip_runtime.h>
#include <math.h>

#define CAMS 6
#define CCH 256
#define HH 46
#define WW 80
#define NPIX (HH * WW)
#define HEADS 8
#define PIP 4
#define PP 4
#define KK 16
#define RADIUS_F 0.12f
#define NC 384        // combined qgemm output width: 256 offsets + 128 logits
#define FEATB (58 * 4 * CAMS)   // feat-transpose blocks in prep
#define QTB (40 * 4)            // query-transpose blocks in prep

__device__ __forceinline__ unsigned short f2bf(float f) {
    unsigned int x = __float_as_uint(f);
    unsigned int r = (x + 0x7FFFu + ((x >> 16) & 1u)) >> 16;  // RNE
    return (unsigned short)r;
}
__device__ __forceinline__ float bf2f(unsigned short u) {
    return __uint_as_float(((unsigned int)u) << 16);
}

// prep2_k:
//  [0, FEATB)            : LDS-tiled feat transpose + bf16 convert
//  [FEATB, FEATB+40)     : weight transposes -> interleaved f4 Wi[kg][col]
//  [FEATB+40, +40+QTB)   : query transpose -> qTi f4[kg][n] (k-group-major)
__global__ void __launch_bounds__(256) prep2_k(const float* __restrict__ imfeat,
                                               unsigned short* __restrict__ feat_t,
                                               const float* __restrict__ offw,
                                               const float* __restrict__ ww,
                                               const float* __restrict__ outw,
                                               const float* __restrict__ query,
                                               float* __restrict__ WCi,
                                               float* __restrict__ outTi,
                                               float* __restrict__ qTi,
                                               int N) {
    __shared__ float tile[64][65];
    int b = blockIdx.x;
    int tj = threadIdx.x & 63;
    int ti = threadIdx.x >> 6;
    if (b < FEATB) {
        int px = b % 58, rest = b / 58;
        int r0 = (rest % 4) * 64;
        int cam = rest / 4;
        int p0 = px * 64;
        const float* src = imfeat + ((long)cam * CCH + r0) * NPIX + p0;
#pragma unroll
        for (int k = 0; k < 64; k += 4) {
            if (p0 + tj < NPIX) tile[ti + k][tj] = src[(long)(ti + k) * NPIX + tj];
        }
        __syncthreads();
        unsigned short* dst = feat_t + ((long)cam * NPIX + p0) * CCH + r0;
#pragma unroll
        for (int k = 0; k < 64; k += 4) {
            if (p0 + ti + k < NPIX) dst[(long)(ti + k) * CCH + tj] = f2bf(tile[tj][ti + k]);
        }
    } else if (b < FEATB + 40) {
        int c = b - FEATB;
        const float* src;
        float* dst;
        int tr, tc, dcols, dcol0;
        if (c < 16)      { src = offw; dst = WCi;   tr = c >> 2;        tc = c & 3;         dcols = NC;  dcol0 = 0; }
        else if (c < 24) { src = ww;   dst = WCi;   tr = (c - 16) & 1;  tc = (c - 16) >> 1; dcols = NC;  dcol0 = 256; }
        else             { src = outw; dst = outTi; tr = (c - 24) >> 2; tc = (c - 24) & 3;  dcols = 256; dcol0 = 0; }
#pragma unroll
        for (int k = 0; k < 64; k += 4)
            tile[ti + k][tj] = src[(long)(tr * 64 + ti + k) * CCH + tc * 64 + tj];
        __syncthreads();
        int col = dcol0 + tr * 64 + tj;
#pragma unroll
        for (int q = ti; q < 16; q += 4) {
            float4 v = make_float4(tile[tj][4 * q + 0], tile[tj][4 * q + 1],
                                   tile[tj][4 * q + 2], tile[tj][4 * q + 3]);
            ((float4*)dst)[(long)(tc * 16 + q) * dcols + col] = v;
        }
    } else {
        int c = b - FEATB - 40;        // 0..159
        int nt = c % 40, ct = c / 40;  // n-tile, c-tile
        int n0 = nt * 64, c0 = ct * 64;
#pragma unroll
        for (int k = 0; k < 64; k += 4) {
            int row = ti + k;
            tile[row][tj] = (n0 + row < N) ? query[(long)(n0 + row) * CCH + c0 + tj] : 0.f;
        }
        __syncthreads();
        int n = n0 + tj;
        if (n < N) {
#pragma unroll
            for (int q = ti; q < 16; q += 4) {
                float4 v = make_float4(tile[tj][4 * q + 0], tile[tj][4 * q + 1],
                                       tile[tj][4 * q + 2], tile[tj][4 * q + 3]);
                ((float4*)qTi)[(long)((c0 >> 2) + q) * N + n] = v;
            }
        }
    }
}

// Dense layer 1: lane = query row. Activations: private coalesced float4
// from qTi (no LDS). Weights: lane-invariant addresses -> scalar loads.
// Per k-group: 1 vload + 8 sloads + 32 FMA -> VALU-bound.
__global__ void __launch_bounds__(256) qgemm7_k(const float* __restrict__ qTi,
                                                const float* __restrict__ WCi,  // f4[64][NC]
                                                const float* __restrict__ offB,
                                                const float* __restrict__ wB,
                                                float* __restrict__ offsets,    // [N][256]
                                                float* __restrict__ wl,         // [N][128]
                                                int N) {
    int n = blockIdx.x * 256 + threadIdx.x;
    int col0 = blockIdx.y * 8;
    int nc = min(n, N - 1);
    const float4* ap = (const float4*)qTi + nc;
    const float4* wp = (const float4*)WCi + col0;
    float acc[8] = {0.f, 0.f, 0.f, 0.f, 0.f, 0.f, 0.f, 0.f};
#pragma unroll 4
    for (int kg = 0; kg < 64; kg++) {
        float4 a = ap[(long)kg * N];
#pragma unroll
        for (int j = 0; j < 8; j++) {
            float4 wv = wp[(long)kg * NC + j];
            acc[j] = fmaf(a.w, wv.w, fmaf(a.z, wv.z, fmaf(a.y, wv.y, fmaf(a.x, wv.x, acc[j]))));
        }
    }
    if (n < N) {
        if (col0 < 256) {
#pragma unroll
            for (int j = 0; j < 8; j++)
                offsets[(long)n * CCH + col0 + j] = tanhf(acc[j] + offB[col0 + j]) * RADIUS_F;
        } else {
#pragma unroll
            for (int j = 0; j < 8; j++)
                wl[(long)n * 128 + (col0 - 256) + j] = acc[j] + wB[(col0 - 256) + j];
        }
    }
}

// Per-(cam,query) sampling. One wave per task; tasks cam-major, partitioned
// into 8 contiguous ranges pinned to XCDs via blockIdx%8 (round-robin
// dispatch). Each XCD touches <=2 cams (<=3.7 MB bf16) -> L2-resident.
__global__ void __launch_bounds__(256, 4) sample_cam_k(
        const unsigned short* __restrict__ feat_t,  // [CAMS][NPIX][CCH] bf16
        const float* __restrict__ refp,             // [CAMS][N][PIP][2]
        const int* __restrict__ bev,                // [CAMS][N][PIP]
        const float* __restrict__ offsets,          // [N][256]
        const float* __restrict__ wl,               // [N][128]
        float* __restrict__ cam_out,                // [CAMS][N][256]
        int N, int per_xcd) {
    int xcd = blockIdx.x & 7;
    int local = (blockIdx.x >> 3) * 4 + (threadIdx.x >> 6);
    if (local >= per_xcd) return;
    long task = (long)xcd * per_xcd + local;
    if (task >= (long)CAMS * N) return;
    int cam = (int)(task / N);
    int n = (int)(task - (long)cam * N);

    int l = threadIdx.x & 63;
    int h = l >> 3;

    const int* bv = bev + ((long)cam * N + n) * 4;
    int m0 = bv[0], m1 = bv[1], m2 = bv[2], m3 = bv[3];
    float* outp = cam_out + ((long)cam * N + n) * CCH + (l << 2);
    if (!(m0 | m1 | m2 | m3)) {
        *(float4*)outp = make_float4(0.f, 0.f, 0.f, 0.f);
        return;
    }

    const float* rp = refp + ((long)cam * N + n) * 8;
    const float4* offn = (const float4*)(offsets + (long)n * CCH + (h << 5));
    const float4* wln = (const float4*)(wl + (long)n * 128 + (h << 4));

    float4 wl0, wl1, wl2, wl3;
    float mmax = -1e30f;
    if (m0) { wl0 = wln[0]; mmax = fmaxf(mmax, fmaxf(fmaxf(wl0.x, wl0.y), fmaxf(wl0.z, wl0.w))); }
    if (m1) { wl1 = wln[1]; mmax = fmaxf(mmax, fmaxf(fmaxf(wl1.x, wl1.y), fmaxf(wl1.z, wl1.w))); }
    if (m2) { wl2 = wln[2]; mmax = fmaxf(mmax, fmaxf(fmaxf(wl2.x, wl2.y), fmaxf(wl2.z, wl2.w))); }
    if (m3) { wl3 = wln[3]; mmax = fmaxf(mmax, fmaxf(fmaxf(wl3.x, wl3.y), fmaxf(wl3.z, wl3.w))); }

    float w_[KK];
#pragma unroll
    for (int k = 0; k < KK; k++) w_[k] = 0.f;
    float ssum = 0.f;
    if (m0) {
        w_[0] = __expf(wl0.x - mmax); w_[1] = __expf(wl0.y - mmax);
        w_[2] = __expf(wl0.z - mmax); w_[3] = __expf(wl0.w - mmax);
        ssum += w_[0] + w_[1] + w_[2] + w_[3];
    }
    if (m1) {
        w_[4] = __expf(wl1.x - mmax); w_[5] = __expf(wl1.y - mmax);
        w_[6] = __expf(wl1.z - mmax); w_[7] = __expf(wl1.w - mmax);
        ssum += w_[4] + w_[5] + w_[6] + w_[7];
    }
    if (m2) {
        w_[8] = __expf(wl2.x - mmax); w_[9] = __expf(wl2.y - mmax);
        w_[10] = __expf(wl2.z - mmax); w_[11] = __expf(wl2.w - mmax);
        ssum += w_[8] + w_[9] + w_[10] + w_[11];
    }
    if (m3) {
        w_[12] = __expf(wl3.x - mmax); w_[13] = __expf(wl3.y - mmax);
        w_[14] = __expf(wl3.z - mmax); w_[15] = __expf(wl3.w - mmax);
        ssum += w_[12] + w_[13] + w_[14] + w_[15];
    }
    float inv = 1.f / ssum;

    const ushort4* fcam = (const ushort4*)(feat_t + (long)cam * NPIX * CCH) + l;
    float ax = 0.f, ay = 0.f, az = 0.f, aw = 0.f;

#pragma unroll
    for (int pip = 0; pip < PIP; pip++) {
        int vis = (pip == 0) ? m0 : (pip == 1) ? m1 : (pip == 2) ? m2 : m3;
        if (!vis) continue;
        float rx = rp[pip * 2 + 0];
        float ry = rp[pip * 2 + 1];
        float4 oa = offn[pip * 2];
        float4 ob = offn[pip * 2 + 1];
        float px[PP] = {oa.x, oa.z, ob.x, ob.z};
        float py[PP] = {oa.y, oa.w, ob.y, ob.w};
#pragma unroll
        for (int p = 0; p < PP; p++) {
            float wgt = w_[pip * PP + p];
            float x = fmaf(rx + px[p], (float)WW, -0.5f);
            float y = fmaf(ry + py[p], (float)HH, -0.5f);
            float x0f = floorf(x), y0f = floorf(y);
            float fx = x - x0f, fy = y - y0f;
            int ix = (int)x0f, iy = (int)y0f;
            int ix0 = min(max(ix, 0), WW - 1);
            int ix1 = min(max(ix + 1, 0), WW - 1);
            int iy0 = min(max(iy, 0), HH - 1);
            int iy1 = min(max(iy + 1, 0), HH - 1);
            float wx0 = (1.f - fx) * (((ix >= 0) & (ix < WW)) ? 1.f : 0.f);
            float wx1 = fx * (((ix + 1 >= 0) & (ix + 1 < WW)) ? 1.f : 0.f);
            float wy0 = (1.f - fy) * (((iy >= 0) & (iy < HH)) ? 1.f : 0.f);
            float wy1 = fy * (((iy + 1 >= 0) & (iy + 1 < HH)) ? 1.f : 0.f);
            const ushort4 u00 = fcam[(iy0 * WW + ix0) * (CCH / 4)];
            const ushort4 u01 = fcam[(iy0 * WW + ix1) * (CCH / 4)];
            const ushort4 u10 = fcam[(iy1 * WW + ix0) * (CCH / 4)];
            const ushort4 u11 = fcam[(iy1 * WW + ix1) * (CCH / 4)];
            float a00 = wgt * wy0 * wx0;
            float a01 = wgt * wy0 * wx1;
            float a10 = wgt * wy1 * wx0;
            float a11 = wgt * wy1 * wx1;
            ax = fmaf(a00, bf2f(u00.x), ax); ay = fmaf(a00, bf2f(u00.y), ay);
            az = fmaf(a00, bf2f(u00.z), az); aw = fmaf(a00, bf2f(u00.w), aw);
            ax = fmaf(a01, bf2f(u01.x), ax); ay = fmaf(a01, bf2f(u01.y), ay);
            az = fmaf(a01, bf2f(u01.z), az); aw = fmaf(a01, bf2f(u01.w), aw);
            ax = fmaf(a10, bf2f(u10.x), ax); ay = fmaf(a10, bf2f(u10.y), ay);
            az = fmaf(a10, bf2f(u10.z), az); aw = fmaf(a10, bf2f(u10.w), aw);
            ax = fmaf(a11, bf2f(u11.x), ax); ay = fmaf(a11, bf2f(u11.y), ay);
            az = fmaf(a11, bf2f(u11.z), az); aw = fmaf(a11, bf2f(u11.w), aw);
        }
    }
    *(float4*)outp = make_float4(ax * inv, ay * inv, az * inv, aw * inv);
}

// camsum + transpose: fsumTi f4[kg][n] = sum_cam cam_out[cam][n][4kg..4kg+3]
// 32 n x 16 kg tile through LDS; coalesced reads and writes.
__global__ void __launch_bounds__(256) camsum_t_k(const float* __restrict__ cam_out,
                                                  float* __restrict__ fsumTi, int N) {
    __shared__ float4 lds[16][33];
    int t = threadIdx.x;
    int n0 = blockIdx.x * 32;
    int kg0 = blockIdx.y * 16;
    const float4* src = (const float4*)cam_out;
#pragma unroll
    for (int pass = 0; pass < 2; pass++) {
        int item = t + pass * 256;
        int row = item >> 4;      // 0..31
        int c = item & 15;        // 0..15
        int n = n0 + row;
        float4 s = make_float4(0.f, 0.f, 0.f, 0.f);
        if (n < N) {
#pragma unroll
            for (int cam = 0; cam < CAMS; cam++) {
                float4 v = src[((long)cam * N + n) * 64 + kg0 + c];
                s.x += v.x; s.y += v.y; s.z += v.z; s.w += v.w;
            }
        }
        lds[c][row] = s;
    }
    __syncthreads();
    float4* dst = (float4*)fsumTi;
#pragma unroll
    for (int pass = 0; pass < 2; pass++) {
        int item = t + pass * 256;
        int k = item >> 5;        // 0..15
        int row = item & 31;
        int n = n0 + row;
        if (n < N) dst[(long)(kg0 + k) * N + n] = lds[k][row];
    }
}

// Dense layer 2: same no-LDS structure; 1/count from coalesced int4 bev loads.
__global__ void __launch_bounds__(256) outproj7_k(const float* __restrict__ fsumTi,
                                                  const int* __restrict__ bev,
                                                  const float* __restrict__ outTi, // f4[64][256]
                                                  const float* __restrict__ outB,
                                                  float* __restrict__ out, int N) {
    int n = blockIdx.x * 256 + threadIdx.x;
    int col0 = blockIdx.y * 8;
    int nc = min(n, N - 1);
    const float4* ap = (const float4*)fsumTi + nc;
    const float4* wp = (const float4*)outTi + col0;
    const int4* bv4 = (const int4*)bev;
    int cnt = 0;
#pragma unroll
    for (int cam = 0; cam < CAMS; cam++) {
        int4 bv = bv4[(long)cam * N + nc];
        cnt += (bv.x | bv.y | bv.z | bv.w) ? 1 : 0;
    }
    float inv = 1.f / (float)max(cnt, 1);
    float acc[8] = {0.f, 0.f, 0.f, 0.f, 0.f, 0.f, 0.f, 0.f};
#pragma unroll 4
    for (int kg = 0; kg < 64; kg++) {
        float4 a = ap[(long)kg * N];
#pragma unroll
        for (int j = 0; j < 8; j++) {
            float4 wv = wp[(long)kg * CCH + j];
            acc[j] = fmaf(a.w, wv.w, fmaf(a.z, wv.z, fmaf(a.y, wv.y, fmaf(a.x, wv.x, acc[j]))));
        }
    }
    if (n < N) {
#pragma unroll
        for (int j = 0; j < 8; j++)
            out[(long)n * CCH + col0 + j] = fmaf(acc[j], inv, outB[col0 + j]);
    }
}

extern "C" void kernel_launch(void* const* d_in, const int* in_sizes, int n_in,
                              void* d_out, int out_size, void* d_ws, size_t ws_size,
                              hipStream_t stream) {
    const float* query    = (const float*)d_in[0];
    const float* imfeat   = (const float*)d_in[1];
    const float* refp     = (const float*)d_in[2];
    const int*   bev      = (const int*)d_in[3];
    const float* offset_w = (const float*)d_in[4];
    const float* offset_b = (const float*)d_in[5];
    const float* weight_w = (const float*)d_in[6];
    const float* weight_b = (const float*)d_in[7];
    const float* out_w    = (const float*)d_in[8];
    const float* out_b    = (const float*)d_in[9];
    float* out = (float*)d_out;

    int N = in_sizes[0] / CCH;  // 2500

    float* ws = (float*)d_ws;
    unsigned short* feat_t = (unsigned short*)ws;              // 6*3680*256 bf16
    float* WCi    = ws + (size_t)CAMS * NPIX * CCH / 2;        // 256*384 (interleaved f4)
    float* outTi  = WCi + (size_t)CCH * NC;                    // 256*256 (interleaved f4)
    float* offs   = outTi + (size_t)CCH * CCH;                 // N*256
    float* wl     = offs + (size_t)N * CCH;                    // N*128
    float* camob  = wl + (size_t)N * 128;                      // CAMS*N*256
    float* qTi    = camob + (size_t)CAMS * N * CCH;            // 64*N*4
    float* fsumTi = qTi + (size_t)64 * N * 4;                  // 64*N*4

    prep2_k<<<FEATB + 40 + QTB, 256, 0, stream>>>(imfeat, feat_t, offset_w, weight_w,
                                                  out_w, query, WCi, outTi, qTi, N);

    int nblk = (N + 255) / 256;   // 10
    qgemm7_k<<<dim3(nblk, 48), 256, 0, stream>>>(qTi, WCi, offset_b, weight_b,
                                                 offs, wl, N);

    int T = CAMS * N;
    int per_xcd = (T + 7) / 8;
    int blocks = 8 * ((per_xcd + 3) / 4);
    sample_cam_k<<<blocks, 256, 0, stream>>>(feat_t, refp, bev, offs, wl, camob,
                                             N, per_xcd);

    camsum_t_k<<<dim3((N + 31) / 32, 4), 256, 0, stream>>>(camob, fsumTi, N);

    outproj7_k<<<dim3(nblk, 32), 256, 0, stream>>>(fsumTi, bev, outTi, out_b, out, N);
}